// Round 1
// baseline (3120.798 us; speedup 1.0000x reference)
//
#include <hip/hip_runtime.h>
#include <hip/hip_bf16.h>
#include <math.h>

#define NE 64
#define TK 8
#define H 2048
#define I 768
#define T 4096
#define NROWS (T * TK)   // 32768
#define LDK 40           // padded LDS k-extent in shorts (80 B rows: 16B-aligned, 2-way banks)

typedef __attribute__((ext_vector_type(8))) short short8;
typedef __attribute__((ext_vector_type(4))) short short4v;
typedef __attribute__((ext_vector_type(4))) int   int4v;
typedef __attribute__((ext_vector_type(4))) float floatx4;

__device__ inline float bits2f(unsigned short s) {
  union { unsigned int u; float f; } v; v.u = ((unsigned int)s) << 16; return v.f;
}
__device__ inline unsigned short f2bf(float f) {  // RNE fp32->bf16
  union { float f; unsigned int u; } v; v.f = f;
  unsigned int r = v.u + 0x7fffu + ((v.u >> 16) & 1u);
  return (unsigned short)(r >> 16);
}

// ---------- dtype detection: even shorts of an fp32 buffer are mantissa bits
// -> random exponents when viewed as bf16. Real bf16 N(0,1) data stays tiny. ----------
__global__ void detect_kernel(const void* __restrict__ buf, int* __restrict__ flag) {
  __shared__ int s;
  int t = threadIdx.x;
  if (t == 0) s = 1;
  __syncthreads();
  unsigned short bits = ((const unsigned short*)buf)[2 * t];
  float v = bits2f(bits);
  if (!(fabsf(v) < 1e4f)) atomicAnd(&s, 0);  // NaN also lands here
  __syncthreads();
  if (t == 0) *flag = s;   // 1 = bf16 buffers, 0 = fp32 buffers
}

// ---------- router: one wave per token, top-8 via shuffle argmax, softmax ----------
__global__ __launch_bounds__(256) void router_kernel(
    const void* __restrict__ logits, const int* __restrict__ flag,
    int* __restrict__ expert_ids, float* __restrict__ w_tk, int* __restrict__ counts) {
  int tok  = blockIdx.x * 4 + (threadIdx.x >> 6);
  int lane = threadIdx.x & 63;
  int isb = *flag;
  float v = isb ? bits2f(((const unsigned short*)logits)[tok * NE + lane])
                : ((const float*)logits)[tok * NE + lane];
  float keep = v;
  float vals[8]; int ids[8];
#pragma unroll
  for (int k = 0; k < TK; ++k) {
    float bv = keep; int bi = lane;
#pragma unroll
    for (int off = 32; off > 0; off >>= 1) {
      float ov = __shfl_xor(bv, off, 64);
      int   oi = __shfl_xor(bi, off, 64);
      if (ov > bv || (ov == bv && oi < bi)) { bv = ov; bi = oi; }  // ties -> lower idx
    }
    vals[k] = bv; ids[k] = bi;
    if (lane == bi) keep = -INFINITY;
  }
  float s = 0.f; float w[8];
#pragma unroll
  for (int k = 0; k < TK; ++k) { w[k] = __expf(vals[k] - vals[0]); s += w[k]; }
  float inv = 1.f / s;
#pragma unroll
  for (int k = 0; k < TK; ++k) {
    if (lane == k) {
      expert_ids[tok * TK + k] = ids[k];
      w_tk[tok * TK + k] = w[k] * inv;
      atomicAdd(&counts[ids[k]], 1);
    }
  }
}

__global__ void scan_kernel(const int* __restrict__ counts,
                            int* __restrict__ offsets, int* __restrict__ cursor) {
  if (threadIdx.x == 0) {
    int s = 0;
    for (int e = 0; e < NE; ++e) { offsets[e] = s; cursor[e] = s; s += counts[e]; }
  }
}

__global__ __launch_bounds__(256) void scatter_kernel(
    const int* __restrict__ expert_ids, const float* __restrict__ w_tk,
    int* __restrict__ cursor, int* __restrict__ tok_of_row,
    float* __restrict__ w_of_row, int* __restrict__ rev) {
  int i = blockIdx.x * 256 + threadIdx.x;
  int e = expert_ids[i];
  int row = atomicAdd(&cursor[e], 1);
  tok_of_row[row] = i >> 3;
  w_of_row[row] = w_tk[i];
  rev[i] = row;
}

// ---------- weight tile stager: W[k][n] (row-major, ldw) tile (32 x 128) ->
// LDS[n][k] packed bf16 pairs. Thread t owns (n = t>>1, k-half = (t&1)*16):
// 16 coalesced dword/ushort column loads, two aligned b128 LDS writes. ----------
__device__ inline void stage_w(const void* __restrict__ W, int ldw, long elem0, int n0,
                               short* __restrict__ lds, int t, int isb) {
  int n = t >> 1, kh = (t & 1) * 16;
  long base = elem0 + (long)kh * ldw + n0 + n;
  int pk[8];
  if (!isb) {
    const float* Wf = (const float*)W + base;
#pragma unroll
    for (int j = 0; j < 8; ++j) {
      float lo = Wf[(long)(2 * j) * ldw];
      float hi = Wf[(long)(2 * j + 1) * ldw];
      pk[j] = (int)f2bf(lo) | ((int)f2bf(hi) << 16);
    }
  } else {
    const unsigned short* Wb = (const unsigned short*)W + base;
#pragma unroll
    for (int j = 0; j < 8; ++j) {
      unsigned int lo = Wb[(long)(2 * j) * ldw];
      unsigned int hi = Wb[(long)(2 * j + 1) * ldw];
      pk[j] = (int)(lo | (hi << 16));
    }
  }
  int* ld = (int*)lds + n * (LDK / 2) + (kh >> 1);
  ((int4v*)ld)[0] = (int4v){pk[0], pk[1], pk[2], pk[3]};
  ((int4v*)ld)[1] = (int4v){pk[4], pk[5], pk[6], pk[7]};
}

// ---------- GEMM1: act[row][0..768) = silu(X*Wg) * (X*Wu), bf16 out ----------
__global__ __launch_bounds__(256, 1) void gemm1_kernel(
    const void* __restrict__ hs, const void* __restrict__ gate_w,
    const void* __restrict__ up_w, const int* __restrict__ flag,
    const int* __restrict__ counts, const int* __restrict__ offsets,
    const int* __restrict__ tok_of_row, short* __restrict__ act) {
  const int e = blockIdx.z, mt = blockIdx.y;
  const int cnt = counts[e];
  if (mt * 128 >= cnt) return;
  const int n0 = blockIdx.x * 128;
  const int off = offsets[e];
  const int t = threadIdx.x;
  const int isb = *flag;

  __shared__ short Xs[128 * LDK];
  __shared__ short Gs[128 * LDK];
  __shared__ short Us[128 * LDK];
  __shared__ int toks[128];

  if (t < 128) {
    int r = mt * 128 + t;
    toks[t] = tok_of_row[off + (r < cnt ? r : 0)];
  }
  __syncthreads();

  const int wave = t >> 6, lane = t & 63;
  const int wm = wave >> 1, wn = wave & 1;
  const int lm = lane & 15, quad = lane >> 4;

  floatx4 accg[4][4], accu[4][4];
#pragma unroll
  for (int a = 0; a < 4; ++a)
#pragma unroll
    for (int b = 0; b < 4; ++b) {
      accg[a][b] = (floatx4){0.f, 0.f, 0.f, 0.f};
      accu[a][b] = (floatx4){0.f, 0.f, 0.f, 0.f};
    }

  const int xr = t >> 1, xh = (t & 1) * 16;
  const long xrow = (long)toks[xr] * H + xh;
  const long wrow0 = (long)e * H * I;

  for (int k0 = 0; k0 < H; k0 += 32) {
    // ---- X gather-stage (rows from token list), fp32->bf16 or direct bf16
    short8 sA, sB;
    if (!isb) {
      const float* xsrc = (const float*)hs + xrow + k0;
      float4 x0 = *(const float4*)(xsrc + 0);
      float4 x1 = *(const float4*)(xsrc + 4);
      float4 x2 = *(const float4*)(xsrc + 8);
      float4 x3 = *(const float4*)(xsrc + 12);
      sA[0] = (short)f2bf(x0.x); sA[1] = (short)f2bf(x0.y);
      sA[2] = (short)f2bf(x0.z); sA[3] = (short)f2bf(x0.w);
      sA[4] = (short)f2bf(x1.x); sA[5] = (short)f2bf(x1.y);
      sA[6] = (short)f2bf(x1.z); sA[7] = (short)f2bf(x1.w);
      sB[0] = (short)f2bf(x2.x); sB[1] = (short)f2bf(x2.y);
      sB[2] = (short)f2bf(x2.z); sB[3] = (short)f2bf(x2.w);
      sB[4] = (short)f2bf(x3.x); sB[5] = (short)f2bf(x3.y);
      sB[6] = (short)f2bf(x3.z); sB[7] = (short)f2bf(x3.w);
    } else {
      const short* xsrc = (const short*)hs + xrow + k0;
      sA = *(const short8*)(xsrc);
      sB = *(const short8*)(xsrc + 8);
    }
    *(short8*)&Xs[xr * LDK + xh]     = sA;
    *(short8*)&Xs[xr * LDK + xh + 8] = sB;

    stage_w(gate_w, I, wrow0 + (long)k0 * I, n0, Gs, t, isb);
    stage_w(up_w,   I, wrow0 + (long)k0 * I, n0, Us, t, isb);
    __syncthreads();

    short8 af[4], gf[4], uf[4];
#pragma unroll
    for (int mi = 0; mi < 4; ++mi)
      af[mi] = *(const short8*)&Xs[(wm * 64 + mi * 16 + lm) * LDK + quad * 8];
#pragma unroll
    for (int ni = 0; ni < 4; ++ni) {
      gf[ni] = *(const short8*)&Gs[(wn * 64 + ni * 16 + lm) * LDK + quad * 8];
      uf[ni] = *(const short8*)&Us[(wn * 64 + ni * 16 + lm) * LDK + quad * 8];
    }
#pragma unroll
    for (int mi = 0; mi < 4; ++mi)
#pragma unroll
      for (int ni = 0; ni < 4; ++ni) {
        accg[mi][ni] = __builtin_amdgcn_mfma_f32_16x16x32_bf16(af[mi], gf[ni], accg[mi][ni], 0, 0, 0);
        accu[mi][ni] = __builtin_amdgcn_mfma_f32_16x16x32_bf16(af[mi], uf[ni], accu[mi][ni], 0, 0, 0);
      }
    __syncthreads();
  }

#pragma unroll
  for (int mi = 0; mi < 4; ++mi)
#pragma unroll
    for (int rr = 0; rr < 4; ++rr) {
      int m = mt * 128 + wm * 64 + mi * 16 + quad * 4 + rr;
      if (m < cnt) {
        short* dst = act + (long)(off + m) * I + n0 + wn * 64 + lm;
#pragma unroll
        for (int ni = 0; ni < 4; ++ni) {
          float g = accg[mi][ni][rr], u = accu[mi][ni][rr];
          float aa = (g / (1.f + __expf(-g))) * u;   // silu(g)*u
          dst[ni * 16] = (short)f2bf(aa);
        }
      }
    }
}

// ---------- GEMM2: scratch2[row][0..2048) = act * Wdown (bf16), or atomic fp32 ----------
__global__ __launch_bounds__(256, 1) void gemm2_kernel(
    const short* __restrict__ act, const void* __restrict__ down_w,
    const int* __restrict__ flag, const int* __restrict__ counts,
    const int* __restrict__ offsets, const int* __restrict__ tok_of_row,
    const float* __restrict__ w_of_row, short* __restrict__ scratch2,
    float* __restrict__ acc_out, int use_atomic) {
  const int e = blockIdx.z, mt = blockIdx.y;
  const int cnt = counts[e];
  if (mt * 128 >= cnt) return;
  const int n0 = blockIdx.x * 128;
  const int off = offsets[e];
  const int t = threadIdx.x;
  const int isb = *flag;

  __shared__ short As[128 * LDK];
  __shared__ short Bs[128 * LDK];

  const int wave = t >> 6, lane = t & 63;
  const int wm = wave >> 1, wn = wave & 1;
  const int lm = lane & 15, quad = lane >> 4;

  floatx4 acc[4][4];
#pragma unroll
  for (int a = 0; a < 4; ++a)
#pragma unroll
    for (int b = 0; b < 4; ++b) acc[a][b] = (floatx4){0.f, 0.f, 0.f, 0.f};

  const int xr = t >> 1, xh = (t & 1) * 16;
  const int rloc = mt * 128 + xr;
  const long arow = (long)(off + (rloc < cnt ? rloc : 0)) * I + xh;
  const long wrow0 = (long)e * I * H;

  for (int k0 = 0; k0 < I; k0 += 32) {
    const short* asrc = act + arow + k0;
    *(short8*)&As[xr * LDK + xh]     = *(const short8*)(asrc);
    *(short8*)&As[xr * LDK + xh + 8] = *(const short8*)(asrc + 8);
    stage_w(down_w, H, wrow0 + (long)k0 * H, n0, Bs, t, isb);
    __syncthreads();

    short8 af[4], bf[4];
#pragma unroll
    for (int mi = 0; mi < 4; ++mi)
      af[mi] = *(const short8*)&As[(wm * 64 + mi * 16 + lm) * LDK + quad * 8];
#pragma unroll
    for (int ni = 0; ni < 4; ++ni)
      bf[ni] = *(const short8*)&Bs[(wn * 64 + ni * 16 + lm) * LDK + quad * 8];
#pragma unroll
    for (int mi = 0; mi < 4; ++mi)
#pragma unroll
      for (int ni = 0; ni < 4; ++ni)
        acc[mi][ni] = __builtin_amdgcn_mfma_f32_16x16x32_bf16(af[mi], bf[ni], acc[mi][ni], 0, 0, 0);
    __syncthreads();
  }

#pragma unroll
  for (int mi = 0; mi < 4; ++mi)
#pragma unroll
    for (int rr = 0; rr < 4; ++rr) {
      int m = mt * 128 + wm * 64 + mi * 16 + quad * 4 + rr;
      if (m < cnt) {
        int grow = off + m;
        if (!use_atomic) {
          short* dst = scratch2 + (long)grow * H + n0 + wn * 64 + lm;
#pragma unroll
          for (int ni = 0; ni < 4; ++ni) dst[ni * 16] = (short)f2bf(acc[mi][ni][rr]);
        } else {
          int tokid = tok_of_row[grow];
          float w = w_of_row[grow];
          float* dst = acc_out + (long)tokid * H + n0 + wn * 64 + lm;
#pragma unroll
          for (int ni = 0; ni < 4; ++ni) atomicAdd(&dst[ni * 16], acc[mi][ni][rr] * w);
        }
      }
    }
}

// ---------- combine: out[t][:] = sum_k w_tk * scratch2[rev[t,k]][:] ----------
__global__ __launch_bounds__(256) void combine_kernel(
    const short* __restrict__ scratch2, const int* __restrict__ rev,
    const float* __restrict__ w_tk, const int* __restrict__ flag,
    void* __restrict__ out) {
  int tok = blockIdx.x;
  int c0 = threadIdx.x * 8;
  float acc[8] = {0.f, 0.f, 0.f, 0.f, 0.f, 0.f, 0.f, 0.f};
#pragma unroll
  for (int k = 0; k < TK; ++k) {
    int row = rev[tok * TK + k];
    float w = w_tk[tok * TK + k];
    short8 v = *(const short8*)(scratch2 + (long)row * H + c0);
#pragma unroll
    for (int j = 0; j < 8; ++j) acc[j] += w * bits2f((unsigned short)v[j]);
  }
  if (*flag) {
    short8 o;
#pragma unroll
    for (int j = 0; j < 8; ++j) o[j] = (short)f2bf(acc[j]);
    *(short8*)((short*)out + (long)tok * H + c0) = o;
  } else {
    float4* o = (float4*)((float*)out + (long)tok * H + c0);
    o[0] = make_float4(acc[0], acc[1], acc[2], acc[3]);
    o[1] = make_float4(acc[4], acc[5], acc[6], acc[7]);
  }
}

// ---------- atomic-path finalize: fp32 accum buffer -> out (dtype per flag) ----------
__global__ __launch_bounds__(256) void cast_out_kernel(
    const float* __restrict__ accb, const int* __restrict__ flag, void* __restrict__ out) {
  int i = (blockIdx.x * 256 + threadIdx.x) * 4;
  float4 v = *(const float4*)(accb + i);
  if (*flag) {
    short4v o;
    o[0] = (short)f2bf(v.x); o[1] = (short)f2bf(v.y);
    o[2] = (short)f2bf(v.z); o[3] = (short)f2bf(v.w);
    *(short4v*)((short*)out + i) = o;
  } else {
    *(float4*)((float*)out + i) = v;
  }
}

extern "C" void kernel_launch(void* const* d_in, const int* in_sizes, int n_in,
                              void* d_out, int out_size, void* d_ws, size_t ws_size,
                              hipStream_t stream) {
  const void* hs     = d_in[0];
  const void* logits = d_in[1];
  const void* gate_w = d_in[2];
  const void* up_w   = d_in[3];
  const void* down_w = d_in[4];

  char* p = (char*)d_ws;
  int*   flag    = (int*)p;
  int*   counts  = (int*)(p + 64);
  int*   offsets = (int*)(p + 320);
  int*   cursor  = (int*)(p + 576);
  p += 1024;
  int*   expert_ids = (int*)p;   p += (long)NROWS * 4;
  float* w_tk       = (float*)p; p += (long)NROWS * 4;
  int*   tok_of_row = (int*)p;   p += (long)NROWS * 4;
  float* w_of_row   = (float*)p; p += (long)NROWS * 4;
  int*   rev        = (int*)p;   p += (long)NROWS * 4;
  short* act        = (short*)p; p += (long)NROWS * I * 2;
  size_t used = (size_t)(p - (char*)d_ws);
  size_t need_scratch2 = (size_t)NROWS * H * 2;
  int use_atomic = (used + need_scratch2 > ws_size) ? 1 : 0;
  short* scratch2 = (short*)p;
  float* acc_out  = (float*)p;   // path-B fp32 accumulator (33.5 MB) shares the slot

  hipMemsetAsync(counts, 0, 256, stream);
  if (use_atomic) hipMemsetAsync(acc_out, 0, (size_t)T * H * 4, stream);

  detect_kernel<<<1, 128, 0, stream>>>(logits, flag);
  router_kernel<<<T / 4, 256, 0, stream>>>(logits, flag, expert_ids, w_tk, counts);
  scan_kernel<<<1, 64, 0, stream>>>(counts, offsets, cursor);
  scatter_kernel<<<NROWS / 256, 256, 0, stream>>>(expert_ids, w_tk, cursor,
                                                  tok_of_row, w_of_row, rev);
  gemm1_kernel<<<dim3(I / 128, T / 128, NE), 256, 0, stream>>>(
      hs, gate_w, up_w, flag, counts, offsets, tok_of_row, act);
  gemm2_kernel<<<dim3(H / 128, T / 128, NE), 256, 0, stream>>>(
      act, down_w, flag, counts, offsets, tok_of_row, w_of_row,
      scratch2, acc_out, use_atomic);
  if (!use_atomic)
    combine_kernel<<<T, 256, 0, stream>>>(scratch2, rev, w_tk, flag, d_out);
  else
    cast_out_kernel<<<(T * H) / 1024, 256, 0, stream>>>(acc_out, flag, d_out);
}